// Round 7
// baseline (252.225 us; speedup 1.0000x reference)
//
#include <hip/hip_runtime.h>
#include <math.h>

// RUL loss: out = theta * sum(score(diff)) + (1-theta) * sqrt(mean(diff^2))
// score(d) = (d<0 ? exp(-d/13) : exp(d/10)) - 1
// N = 16777216 fp32. 128 MB logical read.
//
// R6 post-mortem: nt loads tripled dur (43->126 us) with UNCHANGED
// FETCH_SIZE => nt degrades the request path without de-allocating L3.
// L3-thrash hypothesis dead. Effective read rate is pinned at ~3.1 TB/s
// (invariant across occupancy 40-70%, 2..16 loads in flight/wave) under the
// harness's ~50% L3-hit mix; floor = 128 MB / 3.15 TB/s = 40.6 us.
// R7: revert nt only. Keep R5's proven asm load structure + R6's fused
// last-block finalize (one launch instead of two).

#define RUL_N 16777216
#define PART_BLOCKS 2048
#define BLOCK_THREADS 256
#define GRID_THREADS (PART_BLOCKS * BLOCK_THREADS)
#define ITERS ((RUL_N / 4) / GRID_THREADS)   // = 8, compile-time constant

typedef float v4f __attribute__((ext_vector_type(4)));

// vdst <- mem[sbase + voff]; voff: 32-bit byte-offset VGPR; sbase: uniform
// SGPR pair. Earlyclobber dst (async VMEM vs allocator hazard, see R4).
#define GLOAD4(dst, voff, sbase) \
    asm volatile("global_load_dwordx4 %0, %1, %2" \
                 : "=&v"(dst) : "v"(voff), "s"(sbase))

#define PIN(x) asm volatile("" : "+v"(x))

__global__ __launch_bounds__(BLOCK_THREADS, 2) void rul_fused_kernel(
    const float* __restrict__ pred,
    const float* __restrict__ tru,
    const float* __restrict__ theta_ptr,
    float* __restrict__ out,
    float* __restrict__ partials /* [2*PART_BLOCKS] */,
    unsigned int* __restrict__ counter) {

    const int tid = blockIdx.x * BLOCK_THREADS + threadIdx.x;
    const int v_byte = tid * 16;

    v4f p[ITERS];
    v4f t[ITERS];

    // ---- load phase: 16 dwordx4 in flight per lane ----
#pragma unroll
    for (int k = 0; k < ITERS; ++k) {
        GLOAD4(p[k], v_byte, pred + (size_t)k * GRID_THREADS * 4);
        GLOAD4(t[k], v_byte, tru  + (size_t)k * GRID_THREADS * 4);
    }
    asm volatile("s_waitcnt vmcnt(0)" ::: "memory");
#pragma unroll
    for (int k = 0; k < ITERS; ++k) { PIN(p[k]); PIN(t[k]); }

    // ---- compute ----
    float s_score0 = 0.0f, s_score1 = 0.0f;
    float s_sq0 = 0.0f, s_sq1 = 0.0f;
#pragma unroll
    for (int k = 0; k < ITERS; ++k) {
        float d0 = p[k][0] - t[k][0];
        float d1 = p[k][1] - t[k][1];
        float d2 = p[k][2] - t[k][2];
        float d3 = p[k][3] - t[k][3];

        float e0 = __expf(d0 * (d0 < 0.0f ? (-1.0f / 13.0f) : (1.0f / 10.0f)));
        float e1 = __expf(d1 * (d1 < 0.0f ? (-1.0f / 13.0f) : (1.0f / 10.0f)));
        float e2 = __expf(d2 * (d2 < 0.0f ? (-1.0f / 13.0f) : (1.0f / 10.0f)));
        float e3 = __expf(d3 * (d3 < 0.0f ? (-1.0f / 13.0f) : (1.0f / 10.0f)));

        s_score0 += (e0 - 1.0f) + (e1 - 1.0f);
        s_score1 += (e2 - 1.0f) + (e3 - 1.0f);
        s_sq0 += d0 * d0 + d1 * d1;
        s_sq1 += d2 * d2 + d3 * d3;
    }
    float s_score = s_score0 + s_score1;
    float s_sq = s_sq0 + s_sq1;

    // wave-64 reduce
#pragma unroll
    for (int off = 32; off > 0; off >>= 1) {
        s_score += __shfl_down(s_score, off);
        s_sq += __shfl_down(s_sq, off);
    }

    __shared__ float sm_score[BLOCK_THREADS / 64];
    __shared__ float sm_sq[BLOCK_THREADS / 64];
    __shared__ int sm_last;
    const int wave = threadIdx.x >> 6;
    const int lane = threadIdx.x & 63;
    if (lane == 0) {
        sm_score[wave] = s_score;
        sm_sq[wave] = s_sq;
    }
    __syncthreads();
    if (threadIdx.x == 0) {
        float a = 0.0f, b = 0.0f;
#pragma unroll
        for (int w = 0; w < BLOCK_THREADS / 64; ++w) {
            a += sm_score[w];
            b += sm_sq[w];
        }
        partials[blockIdx.x] = a;
        partials[PART_BLOCKS + blockIdx.x] = b;
        __threadfence();  // publish partials device-scope before ticket
        unsigned int ticket = atomicAdd(counter, 1u);
        sm_last = (ticket == PART_BLOCKS - 1) ? 1 : 0;
    }
    __syncthreads();

    if (sm_last) {
        __threadfence();  // acquire: all partials visible
        float a = 0.0f, b = 0.0f;
#pragma unroll
        for (int i = threadIdx.x; i < PART_BLOCKS; i += BLOCK_THREADS) {
            a += partials[i];
            b += partials[PART_BLOCKS + i];
        }
#pragma unroll
        for (int off = 32; off > 0; off >>= 1) {
            a += __shfl_down(a, off);
            b += __shfl_down(b, off);
        }
        if (lane == 0) {
            sm_score[wave] = a;
            sm_sq[wave] = b;
        }
        __syncthreads();
        if (threadIdx.x == 0) {
            float sa = 0.0f, sb = 0.0f;
#pragma unroll
            for (int w = 0; w < BLOCK_THREADS / 64; ++w) {
                sa += sm_score[w];
                sb += sm_sq[w];
            }
            float theta = theta_ptr[0];
            float rmse = sqrtf(sb * (1.0f / (float)RUL_N));
            out[0] = theta * sa + (1.0f - theta) * rmse;
        }
    }
}

extern "C" void kernel_launch(void* const* d_in, const int* in_sizes, int n_in,
                              void* d_out, int out_size, void* d_ws, size_t ws_size,
                              hipStream_t stream) {
    const float* pred = (const float*)d_in[0];
    const float* tru = (const float*)d_in[1];
    const float* theta = (const float*)d_in[2];
    float* out = (float*)d_out;
    float* partials = (float*)d_ws;                       // 2*PART_BLOCKS floats
    unsigned int* counter = (unsigned int*)((char*)d_ws + 2 * PART_BLOCKS * sizeof(float));

    // ws is poisoned to 0xAA before every launch: zero the ticket counter.
    hipMemsetAsync(counter, 0, sizeof(unsigned int), stream);

    rul_fused_kernel<<<PART_BLOCKS, BLOCK_THREADS, 0, stream>>>(
        pred, tru, theta, out, partials, counter);
}

// Round 8
// 147.412 us; speedup vs baseline: 1.7110x; 1.7110x over previous
//
#include <hip/hip_runtime.h>
#include <math.h>

// RUL loss: out = theta * sum(score(diff)) + (1-theta) * sqrt(mean(diff^2))
// score(d) = (d<0 ? exp(-d/13) : exp(d/10)) - 1
// N = 16777216 fp32. 131 MB logical read (~50% L3-resident after restore).
//
// R7 post-mortem: the R6/R7 regression was the FUSED last-block ticket, not
// nt: 2048 device-scope threadfence+atomicAdd to one address serialize
// cross-XCD (~2048 x ~60ns ~= 120us). Reverted to the two-kernel structure.
// Kernel dur has been invariant 42.4-44us across occupancy 40-70% and
// 2..16 loads/wave in flight => operative ceiling is the ~3.15 TB/s
// read-path (m13 copy ubench per-direction rate); floor 131MB/3.15 = 41.5us.
// R8's single variable: BLOCK_THREADS 256->512 (last untested shape lever).

#define RUL_N 16777216
#define PART_BLOCKS 2048
#define BLOCK_THREADS 512
#define GRID_THREADS (PART_BLOCKS * BLOCK_THREADS)
#define ITERS ((RUL_N / 4) / GRID_THREADS)   // = 4, compile-time constant

__global__ __launch_bounds__(BLOCK_THREADS) void rul_partial_kernel(
    const float* __restrict__ pred,
    const float* __restrict__ tru,
    float* __restrict__ partials /* [2 * PART_BLOCKS] */) {
    const float4* __restrict__ p4 = (const float4*)pred;
    const float4* __restrict__ t4 = (const float4*)tru;

    const int tid = blockIdx.x * BLOCK_THREADS + threadIdx.x;

    float4 p[ITERS];
    float4 t[ITERS];
#pragma unroll
    for (int k = 0; k < ITERS; ++k) {
        p[k] = p4[tid + k * GRID_THREADS];
        t[k] = t4[tid + k * GRID_THREADS];
    }

    float s_score0 = 0.0f, s_score1 = 0.0f;
    float s_sq0 = 0.0f, s_sq1 = 0.0f;
#pragma unroll
    for (int k = 0; k < ITERS; ++k) {
        float d0 = p[k].x - t[k].x;
        float d1 = p[k].y - t[k].y;
        float d2 = p[k].z - t[k].z;
        float d3 = p[k].w - t[k].w;

        float e0 = __expf(d0 * (d0 < 0.0f ? (-1.0f / 13.0f) : (1.0f / 10.0f)));
        float e1 = __expf(d1 * (d1 < 0.0f ? (-1.0f / 13.0f) : (1.0f / 10.0f)));
        float e2 = __expf(d2 * (d2 < 0.0f ? (-1.0f / 13.0f) : (1.0f / 10.0f)));
        float e3 = __expf(d3 * (d3 < 0.0f ? (-1.0f / 13.0f) : (1.0f / 10.0f)));

        s_score0 += (e0 - 1.0f) + (e1 - 1.0f);
        s_score1 += (e2 - 1.0f) + (e3 - 1.0f);
        s_sq0 += d0 * d0 + d1 * d1;
        s_sq1 += d2 * d2 + d3 * d3;
    }
    float s_score = s_score0 + s_score1;
    float s_sq = s_sq0 + s_sq1;

    // wave-64 reduce
#pragma unroll
    for (int off = 32; off > 0; off >>= 1) {
        s_score += __shfl_down(s_score, off);
        s_sq += __shfl_down(s_sq, off);
    }

    __shared__ float sm_score[BLOCK_THREADS / 64];
    __shared__ float sm_sq[BLOCK_THREADS / 64];
    const int wave = threadIdx.x >> 6;
    const int lane = threadIdx.x & 63;
    if (lane == 0) {
        sm_score[wave] = s_score;
        sm_sq[wave] = s_sq;
    }
    __syncthreads();
    if (threadIdx.x == 0) {
        float a = 0.0f, b = 0.0f;
#pragma unroll
        for (int w = 0; w < BLOCK_THREADS / 64; ++w) {
            a += sm_score[w];
            b += sm_sq[w];
        }
        partials[blockIdx.x] = a;
        partials[PART_BLOCKS + blockIdx.x] = b;
    }
}

#define FIN_THREADS 256

__global__ __launch_bounds__(FIN_THREADS) void rul_finalize_kernel(
    const float* __restrict__ partials,
    const float* __restrict__ theta_ptr,
    float* __restrict__ out) {
    float a = 0.0f, b = 0.0f;
#pragma unroll
    for (int i = threadIdx.x; i < PART_BLOCKS; i += FIN_THREADS) {
        a += partials[i];
        b += partials[PART_BLOCKS + i];
    }
#pragma unroll
    for (int off = 32; off > 0; off >>= 1) {
        a += __shfl_down(a, off);
        b += __shfl_down(b, off);
    }
    __shared__ float sm_a[FIN_THREADS / 64];
    __shared__ float sm_b[FIN_THREADS / 64];
    const int wave = threadIdx.x >> 6;
    const int lane = threadIdx.x & 63;
    if (lane == 0) {
        sm_a[wave] = a;
        sm_b[wave] = b;
    }
    __syncthreads();
    if (threadIdx.x == 0) {
        float sa = 0.0f, sb = 0.0f;
#pragma unroll
        for (int w = 0; w < FIN_THREADS / 64; ++w) {
            sa += sm_a[w];
            sb += sm_b[w];
        }
        float theta = theta_ptr[0];
        float rmse = sqrtf(sb * (1.0f / (float)RUL_N));
        out[0] = theta * sa + (1.0f - theta) * rmse;
    }
}

extern "C" void kernel_launch(void* const* d_in, const int* in_sizes, int n_in,
                              void* d_out, int out_size, void* d_ws, size_t ws_size,
                              hipStream_t stream) {
    const float* pred = (const float*)d_in[0];
    const float* tru = (const float*)d_in[1];
    const float* theta = (const float*)d_in[2];
    float* out = (float*)d_out;
    float* partials = (float*)d_ws; // 2 * PART_BLOCKS * 4 = 16 KB

    rul_partial_kernel<<<PART_BLOCKS, BLOCK_THREADS, 0, stream>>>(pred, tru, partials);
    rul_finalize_kernel<<<1, FIN_THREADS, 0, stream>>>(partials, theta, out);
}